// Round 8
// baseline (338.128 us; speedup 1.0000x reference)
//
#include <hip/hip_runtime.h>
#include <stdint.h>

#define D_DIM 256
#define BI 128       // i-rows per block
#define TJ 128       // j-tile
#define CHUNK 4096   // j per block (grid = 64 x 4 = 256 blocks = 1/CU)
#define NT (CHUNK / TJ)   // 32 tiles per chunk

typedef unsigned short ushort_t;
typedef __attribute__((ext_vector_type(8))) short bf16x8;   // 8 bf16 = 4 VGPRs
typedef __attribute__((ext_vector_type(4))) float f32x4;

__device__ __forceinline__ unsigned short f2bf(float f) {
  union { float f; unsigned u; } x; x.f = f;
  unsigned r = x.u + 0x7FFFu + ((x.u >> 16) & 1u);  // round-nearest-even
  return (unsigned short)(r >> 16);
}

__device__ __forceinline__ float fast_sqrt(float x) {
#if __has_builtin(__builtin_amdgcn_sqrtf)
  return __builtin_amdgcn_sqrtf(x);
#else
  return sqrtf(x);
#endif
}
__device__ __forceinline__ float fast_exp2(float x) {
#if __has_builtin(__builtin_amdgcn_exp2f)
  return __builtin_amdgcn_exp2f(x);
#else
  return exp2f(x);
#endif
}

// async global->LDS, 16B per lane. LDS dest = wave-uniform base + lane*16.
__device__ __forceinline__ void g2l16(const void* g, void* l) {
  __builtin_amdgcn_global_load_lds(
      (__attribute__((address_space(1))) void*)(uintptr_t)g,
      (__attribute__((address_space(3))) void*)(unsigned)(uintptr_t)l,
      16, 0, 0);
}

// ---------------- prep: cast + row norms + A-fragment layout, fused ----------------
// block b = 16 rows. Writes Tb (row-major bf16), TbF (fragment-linear), nrm (atomic).
__global__ __launch_bounds__(256) void
prep_AB(const float* __restrict__ G, const float* __restrict__ P,
        ushort_t* __restrict__ Tb, ushort_t* __restrict__ TbF,
        float* __restrict__ nrm, int Bn)
{
  __shared__ ushort_t Ls[16 * 256];
  const int b = blockIdx.x, t = threadIdx.x;
  const int r0 = b * 16, lane = t & 63;
  #pragma unroll
  for (int it = 0; it < 16; it++) {
    const int r = r0 + it;
    const float* src = (r < Bn) ? (G + (size_t)r * D_DIM)
                                : (P + (size_t)(r - Bn) * D_DIM);
    float v = src[t];
    ushort_t u = f2bf(v);
    Tb[(size_t)r * D_DIM + t] = u;
    Ls[it * 256 + t] = u;
    float s = v * v;
    #pragma unroll
    for (int o = 32; o > 0; o >>= 1) s += __shfl_down(s, o, 64);
    if (lane == 0) atomicAdd(&nrm[r], s);
  }
  __syncthreads();
  #pragma unroll
  for (int it = 0; it < 16; it++) {
    int flat = it * 256 + t;                   // [0, 4096)
    int ks = flat >> 9, e = flat & 511;
    int q = e >> 7, m = (e >> 3) & 15, idx = e & 7;
    TbF[(size_t)b * 4096 + flat] = Ls[m * 256 + ks * 32 + q * 8 + idx];
  }
}

// ---- prep: Tb -> TTF (transposed, fragment-linear): block(dgrp16, jstep32)
__global__ __launch_bounds__(256) void
prep_fragT(const ushort_t* __restrict__ Tb, ushort_t* __restrict__ TTF, int Ttot)
{
  __shared__ ushort_t Ts[64][72];
  const int t = threadIdx.x;
  const int j0 = blockIdx.x * 64, d0 = blockIdx.y * 64;
  #pragma unroll
  for (int qq = 0; qq < 16; qq++) {
    int idx = qq * 256 + t;
    int jr = idx >> 6, dc = idx & 63;
    Ts[dc][jr] = Tb[(size_t)(j0 + jr) * D_DIM + d0 + dc];
  }
  __syncthreads();
  #pragma unroll
  for (int it = 0; it < 16; it++) {
    int flat = it * 256 + t;                   // [0, 4096)
    int blk = flat >> 9, e = flat & 511;
    int jsub = blk & 1, dsub = blk >> 1;       // 2 j-steps x 4 d-grps
    int q = e >> 7, m = (e >> 3) & 15, idx = e & 7;
    ushort_t val = Ts[dsub * 16 + m][jsub * 32 + q * 8 + idx];
    const int dgrp = (d0 >> 4) + dsub;
    const int jstep = (j0 >> 5) + jsub;
    TTF[((size_t)dgrp * (Ttot >> 5) + jstep) * 512 + e] = val;
  }
}

// ---------------- fused, producer/consumer specialized ----------------
// 1024 thr / 16 waves / 1 block per CU. 8 producer waves: GEMM1 (S^T 128j x 128i,
// A from TbF global, B from resident Gsm) + exp-epilogue -> Ksm[(t+1)&1].
// 8 consumer waves: GEMM2 (O^T 256d x 128i, A from TTF global, B from Ksm[t&1]).
// Phases overlap: producer VALU/LDS runs concurrently with consumer MFMA.
__global__ __launch_bounds__(1024) void
fused_kernel(const ushort_t* __restrict__ Tb, const ushort_t* __restrict__ TbF,
             const ushort_t* __restrict__ TTF, const float* __restrict__ nrm,
             float* __restrict__ sg, float* __restrict__ sp,
             float* __restrict__ Part, int Bn, int Ttot)
{
  __shared__ ushort_t Gsm[4 * 8192];      // 64 KB resident i-tile: [kq][row][64 ^ swz]
  __shared__ ushort_t Ksm[2][128 * 128];  // 2 x 32 KB kv: [i][128j ^ swz]

  const int t = threadIdx.x;
  const int w = t >> 6, lane = t & 63;
  const int q = lane >> 4, c = lane & 15;
  const int i0 = blockIdx.x * BI;
  const int chunk0 = blockIdx.y * CHUNK;
  const bool gen = (chunk0 < Bn);
  const int swz = (c & 7) * 8;            // per-lane constant XOR
  const int jsteps = Ttot >> 5;

  // ---- stage resident G tile (128 rows x 256 k, swizzled), all waves ----
  const int srow = t >> 3;                               // 0..127
  const int scol = ((t & 7) * 8) ^ ((srow & 7) * 8);     // source col within 64
  {
    const ushort_t* gsrc = Tb + (size_t)(i0 + srow) * D_DIM;
    #pragma unroll
    for (int kq = 0; kq < 4; kq++)
      g2l16(gsrc + kq * 64 + scol, Gsm + kq * 8192 + t * 8);
  }

  // consumer accumulators (64 regs; producers never touch them)
  f32x4 accO[4][4];
  #pragma unroll
  for (int m = 0; m < 4; m++)
    #pragma unroll
    for (int n = 0; n < 4; n++) accO[m][n] = (f32x4)0.f;

  // producer state
  const int pj = w >> 1, pi = w & 1;      // producer: 32j x 64i per wave (4j x 2i grid)
  const int cw = w - 8;
  const int cd = cw >> 1, ci = cw & 1;    // consumer: 64d x 64i per wave (4d x 2i grid)
  float rs[4] = {0.f, 0.f, 0.f, 0.f};
  float ni[4];
  #pragma unroll
  for (int nt = 0; nt < 4; nt++) ni[nt] = nrm[i0 + (w & 1) * 64 + nt * 16 + c];

  __syncthreads();   // Gsm ready

  for (int ph = 0; ph <= NT; ph++) {
    if (w < 8) {
      if (ph < NT) {
        // ================= PRODUCER: tile ph =================
        const int j0g = chunk0 + ph * TJ;
        ushort_t* Kbuf = Ksm[ph & 1];
        f32x4 acc1[2][4];
        #pragma unroll
        for (int m = 0; m < 2; m++)
          #pragma unroll
          for (int n = 0; n < 4; n++) acc1[m][n] = (f32x4)0.f;

        const ushort_t* afp = TbF + ((size_t)((j0g >> 4) + pj * 2) * 8) * 512 + lane * 8;
        #pragma unroll
        for (int ks = 0; ks < 8; ks++) {
          const bf16x8 af0 = *(const bf16x8*)(afp + ks * 512);
          const bf16x8 af1 = *(const bf16x8*)(afp + 4096 + ks * 512);
          #pragma unroll
          for (int nt = 0; nt < 4; nt++) {
            const bf16x8 bf = *(const bf16x8*)&Gsm[(ks >> 1) * 8192 +
                (pi * 64 + nt * 16 + c) * 64 + ((((ks & 1) * 32) + q * 8) ^ swz)];
            acc1[0][nt] = __builtin_amdgcn_mfma_f32_16x16x32_bf16(af0, bf, acc1[0][nt], 0, 0, 0);
            acc1[1][nt] = __builtin_amdgcn_mfma_f32_16x16x32_bf16(af1, bf, acc1[1][nt], 0, 0, 0);
          }
        }
        // epilogue: kv = exp(-dist/20), rowsums, pack -> Kbuf
        #pragma unroll
        for (int mt = 0; mt < 2; mt++) {
          const int jl = pj * 32 + mt * 16 + q * 4;
          const int jb = j0g + jl;
          const float4 njv = *(const float4*)&nrm[jb];
          const float nj[4] = {njv.x, njv.y, njv.z, njv.w};
          #pragma unroll
          for (int nt = 0; nt < 4; nt++) {
            const int il = pi * 64 + nt * 16 + c;
            const int ig = i0 + il;
            uint32_t pb[4];
            #pragma unroll
            for (int reg = 0; reg < 4; reg++) {
              float sq = fmaxf(ni[nt] + nj[reg] - 2.f * acc1[mt][nt][reg], 0.f);
              float dd = fast_sqrt(sq);
              float kv = fast_exp2(dd * -0.07213475204444817f);  // exp(-dd/20)
              if (gen && (jb + reg == ig)) kv = 0.f;
              rs[nt] += kv;
              union { float f; uint32_t u; } uu; uu.f = kv; pb[reg] = uu.u;
            }
            uint2 pk;  // truncating bf16 pack
            pk.x = __builtin_amdgcn_perm(pb[1], pb[0], 0x07060302u);
            pk.y = __builtin_amdgcn_perm(pb[3], pb[2], 0x07060302u);
            *(uint2*)&Kbuf[il * 128 + (jl ^ swz)] = pk;
          }
        }
      }
    } else {
      if (ph > 0) {
        // ================= CONSUMER: tile ph-1 =================
        const int tt = ph - 1;
        const int j0g = chunk0 + tt * TJ;
        const ushort_t* Kbuf = Ksm[tt & 1];
        #pragma unroll
        for (int ks = 0; ks < 4; ks++) {
          bf16x8 a2[4], kf[4];
          #pragma unroll
          for (int mt = 0; mt < 4; mt++)
            a2[mt] = *(const bf16x8*)(TTF + ((size_t)(cd * 4 + mt) * jsteps + (j0g >> 5) + ks) * 512 + lane * 8);
          #pragma unroll
          for (int nt = 0; nt < 4; nt++)
            kf[nt] = *(const bf16x8*)&Kbuf[(ci * 64 + nt * 16 + c) * 128 + ((ks * 32 + q * 8) ^ swz)];
          #pragma unroll
          for (int mt = 0; mt < 4; mt++)
            #pragma unroll
            for (int nt = 0; nt < 4; nt++)
              accO[mt][nt] = __builtin_amdgcn_mfma_f32_16x16x32_bf16(a2[mt], kf[nt], accO[mt][nt], 0, 0, 0);
        }
      }
    }
    __syncthreads();
  }

  if (w < 8) {
    // rowsum partials -> sg/sp
    float* S = gen ? sg : sp;
    #pragma unroll
    for (int nt = 0; nt < 4; nt++) {
      float r = rs[nt];
      r += __shfl_xor(r, 16, 64);
      r += __shfl_xor(r, 32, 64);
      if (lane < 16) atomicAdd(&S[i0 + pi * 64 + nt * 16 + lane], r);
    }
  } else {
    // O^T partials -> Part[chunk][i][d] (f32x4, 16B aligned)
    float* Pdst = Part + (size_t)blockIdx.y * ((size_t)8192 * D_DIM);
    #pragma unroll
    for (int mt = 0; mt < 4; mt++)
      #pragma unroll
      for (int nt = 0; nt < 4; nt++) {
        const int d = cd * 64 + mt * 16 + q * 4;
        const int ig = i0 + ci * 64 + nt * 16 + c;
        *(f32x4*)&Pdst[(size_t)ig * D_DIM + d] = accO[mt][nt];
      }
  }
}

// ---------------- combine: out = sg*sum(pos parts) - sp*sum(gen parts) ----------------
__global__ __launch_bounds__(256) void
combine_kernel(float* __restrict__ out, const float* __restrict__ Part,
               const float* __restrict__ sg, const float* __restrict__ sp)
{
  const size_t idx = (size_t)blockIdx.x * 256 + threadIdx.x;   // f32x4 index
  const size_t qstride = (size_t)8192 * (D_DIM / 4);
  const int i = (int)(idx >> 6);
  const f32x4* p = (const f32x4*)Part;
  f32x4 g0 = p[idx], g1 = p[idx + qstride];
  f32x4 p0 = p[idx + 2 * qstride], p1 = p[idx + 3 * qstride];
  const float sgv = sg[i], spv = sp[i];
  f32x4 r;
  #pragma unroll
  for (int k = 0; k < 4; k++) r[k] = sgv * (p0[k] + p1[k]) - spv * (g0[k] + g1[k]);
  ((f32x4*)out)[idx] = r;
}

extern "C" void kernel_launch(void* const* d_in, const int* in_sizes, int n_in,
                              void* d_out, int out_size, void* d_ws, size_t ws_size,
                              hipStream_t stream)
{
  const float* G = (const float*)d_in[0];
  const float* P = (const float*)d_in[1];
  const int Bn = in_sizes[0] / D_DIM;   // 8192
  const int Xn = in_sizes[1] / D_DIM;   // 8192
  const int Ttot = Bn + Xn;             // 16384

  // workspace (~56.4 MiB)
  uint8_t* ws = (uint8_t*)d_ws;
  size_t off = 0;
  ushort_t* Tb  = (ushort_t*)(ws + off); off += (size_t)Ttot * D_DIM * 2;  // 8 MiB
  ushort_t* TbF = (ushort_t*)(ws + off); off += (size_t)Ttot * D_DIM * 2;  // 8 MiB
  ushort_t* TTF = (ushort_t*)(ws + off); off += (size_t)Ttot * D_DIM * 2;  // 8 MiB
  float* nrm = (float*)(ws + off); off += (size_t)Ttot * 4;
  float* sg  = (float*)(ws + off); off += (size_t)Bn * 4;
  float* sp  = (float*)(ws + off); off += (size_t)Bn * 4;
  off = (off + 255) & ~(size_t)255;
  float* Part = (float*)(ws + off); off += (size_t)4 * Bn * D_DIM * 4;     // 32 MiB
  if (ws_size < off) return;  // clean-fail signature if ws too small

  // zero nrm + sg + sp (contiguous)
  hipMemsetAsync(nrm, 0, ((size_t)Ttot + 2 * (size_t)Bn) * sizeof(float), stream);

  prep_AB<<<Ttot / 16, 256, 0, stream>>>(G, P, Tb, TbF, nrm, Bn);
  prep_fragT<<<dim3(Ttot / 64, D_DIM / 64), 256, 0, stream>>>(Tb, TTF, Ttot);
  fused_kernel<<<dim3(Bn / BI, Ttot / CHUNK), 1024, 0, stream>>>(
      Tb, TbF, TTF, nrm, sg, sp, Part, Bn, Ttot);
  combine_kernel<<<(Bn * D_DIM / 4) / 256, 256, 0, stream>>>((float*)d_out, Part, sg, sp);
}

// Round 9
// 226.601 us; speedup vs baseline: 1.4922x; 1.4922x over previous
//
#include <hip/hip_runtime.h>
#include <stdint.h>

#define D_DIM 256
#define BI 128       // i-rows per block
#define TJ 128       // j-tile
#define CHUNK 4096   // j per block (grid = 64 x 4 = 256 blocks = 1/CU)

typedef unsigned short ushort_t;
typedef __attribute__((ext_vector_type(8))) short bf16x8;   // 8 bf16 = 4 VGPRs
typedef __attribute__((ext_vector_type(4))) float f32x4;

__device__ __forceinline__ unsigned short f2bf(float f) {
  union { float f; unsigned u; } x; x.f = f;
  unsigned r = x.u + 0x7FFFu + ((x.u >> 16) & 1u);  // round-nearest-even
  return (unsigned short)(r >> 16);
}

__device__ __forceinline__ float fast_sqrt(float x) {
#if __has_builtin(__builtin_amdgcn_sqrtf)
  return __builtin_amdgcn_sqrtf(x);
#else
  return sqrtf(x);
#endif
}
__device__ __forceinline__ float fast_exp2(float x) {
#if __has_builtin(__builtin_amdgcn_exp2f)
  return __builtin_amdgcn_exp2f(x);
#else
  return exp2f(x);
#endif
}

// async global->LDS, 16B per lane. LDS dest = wave-uniform base + lane*16.
__device__ __forceinline__ void g2l16(const void* g, void* l) {
  __builtin_amdgcn_global_load_lds(
      (__attribute__((address_space(1))) void*)(uintptr_t)g,
      (__attribute__((address_space(3))) void*)(unsigned)(uintptr_t)l,
      16, 0, 0);
}

// ---------------- prep: cast + row norms + A-fragment layout, fused ----------------
__global__ __launch_bounds__(256) void
prep_AB(const float* __restrict__ G, const float* __restrict__ P,
        ushort_t* __restrict__ Tb, ushort_t* __restrict__ TbF,
        float* __restrict__ nrm, int Bn)
{
  __shared__ ushort_t Ls[16 * 256];
  const int b = blockIdx.x, t = threadIdx.x;
  const int r0 = b * 16, lane = t & 63;
  #pragma unroll
  for (int it = 0; it < 16; it++) {
    const int r = r0 + it;
    const float* src = (r < Bn) ? (G + (size_t)r * D_DIM)
                                : (P + (size_t)(r - Bn) * D_DIM);
    float v = src[t];
    ushort_t u = f2bf(v);
    Tb[(size_t)r * D_DIM + t] = u;
    Ls[it * 256 + t] = u;
    float s = v * v;
    #pragma unroll
    for (int o = 32; o > 0; o >>= 1) s += __shfl_down(s, o, 64);
    if (lane == 0) atomicAdd(&nrm[r], s);
  }
  __syncthreads();
  #pragma unroll
  for (int it = 0; it < 16; it++) {
    int flat = it * 256 + t;                   // [0, 4096)
    int ks = flat >> 9, e = flat & 511;
    int q = e >> 7, m = (e >> 3) & 15, idx = e & 7;
    TbF[(size_t)b * 4096 + flat] = Ls[m * 256 + ks * 32 + q * 8 + idx];
  }
}

// ---- prep: Tb -> TTF (transposed, fragment-linear): block(dgrp16, jstep32)
__global__ __launch_bounds__(256) void
prep_fragT(const ushort_t* __restrict__ Tb, ushort_t* __restrict__ TTF, int Ttot)
{
  __shared__ ushort_t Ts[64][72];
  const int t = threadIdx.x;
  const int j0 = blockIdx.x * 64, d0 = blockIdx.y * 64;
  #pragma unroll
  for (int qq = 0; qq < 16; qq++) {
    int idx = qq * 256 + t;
    int jr = idx >> 6, dc = idx & 63;
    Ts[dc][jr] = Tb[(size_t)(j0 + jr) * D_DIM + d0 + dc];
  }
  __syncthreads();
  #pragma unroll
  for (int it = 0; it < 16; it++) {
    int flat = it * 256 + t;                   // [0, 4096)
    int blk = flat >> 9, e = flat & 511;
    int jsub = blk & 1, dsub = blk >> 1;       // 2 j-steps x 4 d-grps
    int q = e >> 7, m = (e >> 3) & 15, idx = e & 7;
    ushort_t val = Ts[dsub * 16 + m][jsub * 32 + q * 8 + idx];
    const int dgrp = (d0 >> 4) + dsub;
    const int jstep = (j0 >> 5) + jsub;
    TTF[((size_t)dgrp * (Ttot >> 5) + jstep) * 512 + e] = val;
  }
}

// ---------------- fused: S^T -> kv (LDS dbuf) -> O^T, 1 barrier/tile ----------------
// Round-7 structure + manual register pipelining:
//   GEMM1 af (global TbF stream) double-buffered 1 ks ahead; first af of the NEXT
//   tile issued during GEMM2 (no barrier in between -> stays in flight).
//   GEMM2 a2 (global TTF stream) double-buffered 1 ks ahead, first pair issued
//   right after the barrier. kf (LDS) single-buffered (4 indep reads/iter).
//   nrm[j] float4s prefetched at tile start, consumed in epilogue.
__global__ __launch_bounds__(1024, 4) void
fused_kernel(const ushort_t* __restrict__ Tb, const ushort_t* __restrict__ TbF,
             const ushort_t* __restrict__ TTF, const float* __restrict__ nrm,
             float* __restrict__ sg, float* __restrict__ sp,
             float* __restrict__ Part, int Bn, int Ttot)
{
  __shared__ ushort_t Gsm[4 * 8192];      // 64 KB resident i-tile: [kq][row][64 ^ swz]
  __shared__ ushort_t Ksm[2][128 * 128];  // 2 x 32 KB kv: [i][128j ^ swz]

  const int t = threadIdx.x;
  const int w = t >> 6, lane = t & 63;
  const int q = lane >> 4, c = lane & 15;
  const int wj = w >> 2, wcol = w & 3;    // GEMM1 4x4 wave grid (32j x 32i each)
  const int wd = w >> 1, wi = w & 1;      // GEMM2 8x2 wave grid (32d x 64i each)
  const int i0 = blockIdx.x * BI;
  const int chunk0 = blockIdx.y * CHUNK;
  const bool gen = (chunk0 < Bn);
  const int swz = (c & 7) * 8;            // per-lane constant XOR
  const int jsteps = Ttot >> 5;

  // ---- stage resident G tile (128 rows x 256 k, swizzled) ----
  const int srow = t >> 3;                               // 0..127
  const int scol = ((t & 7) * 8) ^ ((srow & 7) * 8);     // source col within 64
  {
    const ushort_t* gsrc = Tb + (size_t)(i0 + srow) * D_DIM;
    #pragma unroll
    for (int kq = 0; kq < 4; kq++)
      g2l16(gsrc + kq * 64 + scol, Gsm + kq * 8192 + t * 8);
  }

  f32x4 accO[2][4];
  #pragma unroll
  for (int m = 0; m < 2; m++)
    #pragma unroll
    for (int n = 0; n < 4; n++) accO[m][n] = (f32x4)0.f;
  float rs[2] = {0.f, 0.f};
  float ni[2];
  #pragma unroll
  for (int nt = 0; nt < 2; nt++) ni[nt] = nrm[i0 + wcol * 32 + nt * 16 + c];

  // persistent GEMM1 af prefetch registers (ks=0 of current tile)
  bf16x8 af0c, af1c;
  {
    const ushort_t* ap = TbF + ((size_t)((chunk0 >> 4) + wj * 2) * 8) * 512 + lane * 8;
    af0c = *(const bf16x8*)ap;
    af1c = *(const bf16x8*)(ap + 4096);
  }

  __syncthreads();   // Gsm ready

  for (int jt = 0; jt < CHUNK; jt += TJ) {
    const int j0g = chunk0 + jt;
    ushort_t* Kbuf = Ksm[(jt >> 7) & 1];
    const ushort_t* afp = TbF + ((size_t)((j0g >> 4) + wj * 2) * 8) * 512 + lane * 8;

    // prefetch nrm[j] for this tile's epilogue (hidden under GEMM1)
    float4 njv[2];
    #pragma unroll
    for (int mt = 0; mt < 2; mt++)
      njv[mt] = *(const float4*)&nrm[j0g + wj * 32 + mt * 16 + q * 4];

    // ---- GEMM1: S^T[j32 x i32] per wave, K=256; af global (dbuf), bf from Gsm ----
    f32x4 acc1[2][2];
    #pragma unroll
    for (int m = 0; m < 2; m++)
      #pragma unroll
      for (int n = 0; n < 2; n++) acc1[m][n] = (f32x4)0.f;

    #pragma unroll
    for (int ks = 0; ks < 8; ks++) {
      bf16x8 afn0, afn1;
      if (ks < 7) {
        afn0 = *(const bf16x8*)(afp + (ks + 1) * 512);
        afn1 = *(const bf16x8*)(afp + 4096 + (ks + 1) * 512);
      }
      bf16x8 bf[2];
      #pragma unroll
      for (int nt = 0; nt < 2; nt++)
        bf[nt] = *(const bf16x8*)&Gsm[(ks >> 1) * 8192 + (wcol * 32 + nt * 16 + c) * 64 + ((((ks & 1) * 32) + q * 8) ^ swz)];
      #pragma unroll
      for (int nt = 0; nt < 2; nt++) {
        acc1[0][nt] = __builtin_amdgcn_mfma_f32_16x16x32_bf16(af0c, bf[nt], acc1[0][nt], 0, 0, 0);
        acc1[1][nt] = __builtin_amdgcn_mfma_f32_16x16x32_bf16(af1c, bf[nt], acc1[1][nt], 0, 0, 0);
      }
      if (ks < 7) { af0c = afn0; af1c = afn1; }
    }

    // ---- epilogue: kv = exp(-dist/20), rowsums, pack -> Kbuf ----
    #pragma unroll
    for (int mt = 0; mt < 2; mt++) {
      const int jl = wj * 32 + mt * 16 + q * 4;   // local j of reg 0
      const int jb = j0g + jl;                    // global j
      const float nj[4] = {njv[mt].x, njv[mt].y, njv[mt].z, njv[mt].w};
      #pragma unroll
      for (int nt = 0; nt < 2; nt++) {
        const int il = wcol * 32 + nt * 16 + c;
        const int ig = i0 + il;
        uint32_t pb[4];
        #pragma unroll
        for (int reg = 0; reg < 4; reg++) {
          float sq = fmaxf(ni[nt] + nj[reg] - 2.f * acc1[mt][nt][reg], 0.f);
          float dd = fast_sqrt(sq);
          float kv = fast_exp2(dd * -0.07213475204444817f);  // exp(-dd/20)
          if (gen && (jb + reg == ig)) kv = 0.f;
          rs[nt] += kv;
          union { float f; uint32_t u; } uu; uu.f = kv; pb[reg] = uu.u;
        }
        uint2 pk;  // truncating bf16 pack
        pk.x = __builtin_amdgcn_perm(pb[1], pb[0], 0x07060302u);
        pk.y = __builtin_amdgcn_perm(pb[3], pb[2], 0x07060302u);
        *(uint2*)&Kbuf[il * 128 + (jl ^ swz)] = pk;
      }
    }
    __syncthreads();   // Kbuf ready (sole barrier; dbuf covers cross-tile reuse)

    // ---- GEMM2: O^T[d32 x i64] per wave, K=128; a2 global (dbuf), kf from Kbuf ----
    const ushort_t* a2p = TTF + ((size_t)(wd * 2) * jsteps + (j0g >> 5)) * 512 + lane * 8;
    const size_t mstride = (size_t)jsteps * 512;
    bf16x8 a20 = *(const bf16x8*)a2p;
    bf16x8 a21 = *(const bf16x8*)(a2p + mstride);

    // issue next tile's GEMM1 ks=0 af prefetch (stays in flight through GEMM2)
    {
      const int jn = (jt + TJ < CHUNK) ? (j0g + TJ) : chunk0;
      const ushort_t* ap = TbF + ((size_t)((jn >> 4) + wj * 2) * 8) * 512 + lane * 8;
      af0c = *(const bf16x8*)ap;
      af1c = *(const bf16x8*)(ap + 4096);
    }

    #pragma unroll
    for (int ks = 0; ks < 4; ks++) {
      bf16x8 a2n0, a2n1;
      if (ks < 3) {
        a2n0 = *(const bf16x8*)(a2p + (ks + 1) * 512);
        a2n1 = *(const bf16x8*)(a2p + mstride + (ks + 1) * 512);
      }
      bf16x8 kf[4];
      #pragma unroll
      for (int nt = 0; nt < 4; nt++)
        kf[nt] = *(const bf16x8*)&Kbuf[(wi * 64 + nt * 16 + c) * 128 + ((ks * 32 + q * 8) ^ swz)];
      #pragma unroll
      for (int nt = 0; nt < 4; nt++) {
        accO[0][nt] = __builtin_amdgcn_mfma_f32_16x16x32_bf16(a20, kf[nt], accO[0][nt], 0, 0, 0);
        accO[1][nt] = __builtin_amdgcn_mfma_f32_16x16x32_bf16(a21, kf[nt], accO[1][nt], 0, 0, 0);
      }
      if (ks < 3) { a20 = a2n0; a21 = a2n1; }
    }
    // no barrier: next tile writes the other Ksm buffer
  }

  // rowsum partials -> sg/sp
  float* S = gen ? sg : sp;
  #pragma unroll
  for (int nt = 0; nt < 2; nt++) {
    float r = rs[nt];
    r += __shfl_xor(r, 16, 64);
    r += __shfl_xor(r, 32, 64);
    if (lane < 16) atomicAdd(&S[i0 + wcol * 32 + nt * 16 + lane], r);
  }
  // O^T partials -> Part[chunk][i][d] (f32x4, 16B aligned)
  float* Pdst = Part + (size_t)blockIdx.y * ((size_t)8192 * D_DIM);
  #pragma unroll
  for (int mt = 0; mt < 2; mt++)
    #pragma unroll
    for (int nt = 0; nt < 4; nt++) {
      const int d = wd * 32 + mt * 16 + q * 4;
      const int ig = i0 + wi * 64 + nt * 16 + c;
      *(f32x4*)&Pdst[(size_t)ig * D_DIM + d] = accO[mt][nt];
    }
}

// ---------------- combine: out = sg*sum(pos parts) - sp*sum(gen parts) ----------------
__global__ __launch_bounds__(256) void
combine_kernel(float* __restrict__ out, const float* __restrict__ Part,
               const float* __restrict__ sg, const float* __restrict__ sp)
{
  const size_t idx = (size_t)blockIdx.x * 256 + threadIdx.x;   // f32x4 index
  const size_t qstride = (size_t)8192 * (D_DIM / 4);
  const int i = (int)(idx >> 6);
  const f32x4* p = (const f32x4*)Part;
  f32x4 g0 = p[idx], g1 = p[idx + qstride];
  f32x4 p0 = p[idx + 2 * qstride], p1 = p[idx + 3 * qstride];
  const float sgv = sg[i], spv = sp[i];
  f32x4 r;
  #pragma unroll
  for (int k = 0; k < 4; k++) r[k] = sgv * (p0[k] + p1[k]) - spv * (g0[k] + g1[k]);
  ((f32x4*)out)[idx] = r;
}

extern "C" void kernel_launch(void* const* d_in, const int* in_sizes, int n_in,
                              void* d_out, int out_size, void* d_ws, size_t ws_size,
                              hipStream_t stream)
{
  const float* G = (const float*)d_in[0];
  const float* P = (const float*)d_in[1];
  const int Bn = in_sizes[0] / D_DIM;   // 8192
  const int Xn = in_sizes[1] / D_DIM;   // 8192
  const int Ttot = Bn + Xn;             // 16384

  // workspace (~56.4 MiB)
  uint8_t* ws = (uint8_t*)d_ws;
  size_t off = 0;
  ushort_t* Tb  = (ushort_t*)(ws + off); off += (size_t)Ttot * D_DIM * 2;  // 8 MiB
  ushort_t* TbF = (ushort_t*)(ws + off); off += (size_t)Ttot * D_DIM * 2;  // 8 MiB
  ushort_t* TTF = (ushort_t*)(ws + off); off += (size_t)Ttot * D_DIM * 2;  // 8 MiB
  float* nrm = (float*)(ws + off); off += (size_t)Ttot * 4;
  float* sg  = (float*)(ws + off); off += (size_t)Bn * 4;
  float* sp  = (float*)(ws + off); off += (size_t)Bn * 4;
  off = (off + 255) & ~(size_t)255;
  float* Part = (float*)(ws + off); off += (size_t)4 * Bn * D_DIM * 4;     // 32 MiB
  if (ws_size < off) return;  // clean-fail signature if ws too small

  // zero nrm + sg + sp (contiguous)
  hipMemsetAsync(nrm, 0, ((size_t)Ttot + 2 * (size_t)Bn) * sizeof(float), stream);

  prep_AB<<<Ttot / 16, 256, 0, stream>>>(G, P, Tb, TbF, nrm, Bn);
  prep_fragT<<<dim3(Ttot / 64, D_DIM / 64), 256, 0, stream>>>(Tb, TTF, Ttot);
  fused_kernel<<<dim3(Bn / BI, Ttot / CHUNK), 1024, 0, stream>>>(
      Tb, TbF, TTF, nrm, sg, sp, Part, Bn, Ttot);
  combine_kernel<<<(Bn * D_DIM / 4) / 256, 256, 0, stream>>>((float*)d_out, Part, sg, sp);
}